// Round 5
// baseline (86.363 us; speedup 1.0000x reference)
//
#include <hip/hip_runtime.h>
#include <hip/hip_bf16.h>

using f32x4   = __attribute__((ext_vector_type(4))) float;
using bf16x8  = __attribute__((ext_vector_type(8))) short;
using ushort8 = __attribute__((ext_vector_type(8))) unsigned short;

constexpr int N_ = 512;
constexpr int K_ = 512;
constexpr int NKC = K_ / 32;  // 16 MFMA k-groups

__device__ inline ushort f2bf(float f) {
  union { __hip_bfloat16 h; ushort u; } c;
  c.h = __float2bfloat16(f);
  return c.u;
}

// ---- pre-kernel: pack W[512][512] fp32 -> fragment-linear bf16 ----
// frag f = n_tile*16 + kc ; lane l holds W[n_tile*16 + (l&15)][kc*32 + (l>>4)*8 ..+8]
// 64 lanes x 16 B contiguous = 1 KB per frag.
__global__ __launch_bounds__(256)
void pack_w(const float* __restrict__ W, ushort* __restrict__ P) {
  const int tau = blockIdx.x * 256 + threadIdx.x;   // 0..32767
  const int l = tau & 63, f = tau >> 6;
  const int row = (f >> 4) * 16 + (l & 15);
  const int kb  = (f & 15) * 32 + (l >> 4) * 8;
  const float* s = W + (size_t)row * K_ + kb;
  f32x4 v0 = *reinterpret_cast<const f32x4*>(s);
  f32x4 v1 = *reinterpret_cast<const f32x4*>(s + 4);
  ushort8 o;
  o[0] = f2bf(v0.x); o[1] = f2bf(v0.y); o[2] = f2bf(v0.z); o[3] = f2bf(v0.w);
  o[4] = f2bf(v1.x); o[5] = f2bf(v1.y); o[6] = f2bf(v1.z); o[7] = f2bf(v1.w);
  *reinterpret_cast<ushort8*>(P + (size_t)tau * 8) = o;
}

// ---- main GEMM: no LDS, no barriers; A direct-from-global with in-reg cvt ----
// block = 128 rows x 64 cols, 4 waves stacked along M (wave tile 32x64).
__global__ __launch_bounds__(256, 4)
void gemm_reg(const float* __restrict__ X, const ushort* __restrict__ Wp,
              float* __restrict__ C) {
  const int t    = threadIdx.x;
  const int lane = t & 63;
  const int wr   = t >> 6;      // 0..3

  // XCD-aware bijective swizzle: 2048 blocks = 8 XCDs x 256. Consecutive
  // logical tiles iterate bn fastest -> a row-panel's 8 blocks share an XCD L2.
  const int cpx = gridDim.x >> 3;
  const int bid = (blockIdx.x & 7) * cpx + (blockIdx.x >> 3);
  const int bn  = bid & 7;      // 8 col tiles (512/64)
  const int bm  = bid >> 3;
  const int m0 = bm * 128, n0 = bn * 64;

  // A: per-lane base. row = m0 + wr*32 + mi*16 + (lane&15); k = kc*32 + (lane>>4)*8
  const float*  ap = X + (size_t)(m0 + wr * 32 + (lane & 15)) * K_ + ((lane >> 4) * 8);
  // B: packed frag base for n_tile = bn*4 + ni, kc
  const ushort* bp = Wp + (size_t)(bn * 4) * 16 * 512 + lane * 8;

  f32x4  acc[2][4] = {};
  f32x4  a[2][2][2];   // [buf][mi][half]
  bf16x8 b[2][4];      // [buf][ni]

  auto LDA = [&](int buf, int kc) {
#pragma unroll
    for (int mi = 0; mi < 2; ++mi) {
      const float* p = ap + (size_t)mi * 16 * K_ + kc * 32;
      a[buf][mi][0] = *reinterpret_cast<const f32x4*>(p);
      a[buf][mi][1] = *reinterpret_cast<const f32x4*>(p + 4);
    }
  };
  auto LDB = [&](int buf, int kc) {
#pragma unroll
    for (int ni = 0; ni < 4; ++ni)
      b[buf][ni] = *reinterpret_cast<const bf16x8*>(bp + (size_t)(ni * 16 + kc) * 512);
  };

  LDA(0, 0);
  LDB(0, 0);

#pragma unroll
  for (int kc = 0; kc < NKC; ++kc) {
    const int cur = kc & 1, nxt = cur ^ 1;
    if (kc + 1 < NKC) { LDA(nxt, kc + 1); LDB(nxt, kc + 1); }  // 1-deep prefetch

    bf16x8 fa[2];
#pragma unroll
    for (int mi = 0; mi < 2; ++mi) {
      bf16x8 r;
      r[0] = (short)f2bf(a[cur][mi][0].x); r[1] = (short)f2bf(a[cur][mi][0].y);
      r[2] = (short)f2bf(a[cur][mi][0].z); r[3] = (short)f2bf(a[cur][mi][0].w);
      r[4] = (short)f2bf(a[cur][mi][1].x); r[5] = (short)f2bf(a[cur][mi][1].y);
      r[6] = (short)f2bf(a[cur][mi][1].z); r[7] = (short)f2bf(a[cur][mi][1].w);
      fa[mi] = r;
    }
#pragma unroll
    for (int mi = 0; mi < 2; ++mi)
#pragma unroll
      for (int ni = 0; ni < 4; ++ni)
        acc[mi][ni] = __builtin_amdgcn_mfma_f32_16x16x32_bf16(fa[mi], b[cur][ni],
                                                              acc[mi][ni], 0, 0, 0);
  }

  // store: C/D layout col = lane&15, row = (lane>>4)*4 + reg
  const int col0 = n0 + (lane & 15);
  const int rsub = (lane >> 4) * 4;
#pragma unroll
  for (int mi = 0; mi < 2; ++mi)
#pragma unroll
    for (int ni = 0; ni < 4; ++ni)
#pragma unroll
      for (int r = 0; r < 4; ++r)
        C[(size_t)(m0 + wr * 32 + mi * 16 + rsub + r) * N_ + (col0 + ni * 16)] =
            acc[mi][ni][r];
}

// ---- fallback (round-3 kernel) if ws is too small for the W pack ----
constexpr int BM = 128, BN = 128;
constexpr int LDSK = 72;
constexpr int NKS = 8;

__global__ __launch_bounds__(512, 4)
void gemm_fb(const float* __restrict__ X, const float* __restrict__ W,
             float* __restrict__ C) {
  __shared__ ushort As[2][BM * LDSK];
  __shared__ ushort Bs[2][BN * LDSK];
  const int t = threadIdx.x, lane = t & 63, wave = t >> 6;
  const int wr = wave >> 2, wc = wave & 3;
  const int cpx = gridDim.x >> 3;
  const int bid = (blockIdx.x & 7) * cpx + (blockIdx.x >> 3);
  const int bn = bid & 3, bm = bid >> 2;
  const int m0 = bm * BM, n0 = bn * BN;
  const int sr = t >> 4, sc = (t & 15) * 4;
  const float* xp = X + (size_t)(m0 + sr) * K_ + sc;
  const float* wp = W + (size_t)(n0 + sr) * K_ + sc;
  f32x4 acc[4][2] = {};
  f32x4 ra[2][4], rb[2][4];
  auto LOAD = [&](int set, int ks) {
#pragma unroll
    for (int i = 0; i < 4; ++i) {
      ra[set][i] = *reinterpret_cast<const f32x4*>(xp + (size_t)(i * 32) * K_ + ks * 64);
      rb[set][i] = *reinterpret_cast<const f32x4*>(wp + (size_t)(i * 32) * K_ + ks * 64);
    }
  };
  auto STAGE = [&](int set, int buf) {
#pragma unroll
    for (int i = 0; i < 4; ++i) {
      ushort4 ha, hb;
      ha.x = f2bf(ra[set][i].x); ha.y = f2bf(ra[set][i].y);
      ha.z = f2bf(ra[set][i].z); ha.w = f2bf(ra[set][i].w);
      hb.x = f2bf(rb[set][i].x); hb.y = f2bf(rb[set][i].y);
      hb.z = f2bf(rb[set][i].z); hb.w = f2bf(rb[set][i].w);
      *reinterpret_cast<ushort4*>(&As[buf][(sr + 32 * i) * LDSK + sc]) = ha;
      *reinterpret_cast<ushort4*>(&Bs[buf][(sr + 32 * i) * LDSK + sc]) = hb;
    }
  };
  auto MMA = [&](int buf) {
#pragma unroll
    for (int kk = 0; kk < 2; ++kk) {
      const int kof = kk * 32 + (lane >> 4) * 8;
      bf16x8 aa[4], bb[2];
#pragma unroll
      for (int mi = 0; mi < 4; ++mi)
        aa[mi] = *reinterpret_cast<const bf16x8*>(
            &As[buf][(wr * 64 + mi * 16 + (lane & 15)) * LDSK + kof]);
#pragma unroll
      for (int ni = 0; ni < 2; ++ni)
        bb[ni] = *reinterpret_cast<const bf16x8*>(
            &Bs[buf][(wc * 32 + ni * 16 + (lane & 15)) * LDSK + kof]);
#pragma unroll
      for (int mi = 0; mi < 4; ++mi)
#pragma unroll
        for (int ni = 0; ni < 2; ++ni)
          acc[mi][ni] = __builtin_amdgcn_mfma_f32_16x16x32_bf16(aa[mi], bb[ni],
                                                                acc[mi][ni], 0, 0, 0);
    }
  };
  LOAD(0, 0); LOAD(1, 1); STAGE(0, 0);
  __syncthreads();
#pragma unroll
  for (int ks = 0; ks < NKS - 1; ++ks) {
    if (ks + 2 < NKS) LOAD(ks & 1, ks + 2);
    MMA(ks & 1);
    STAGE((ks + 1) & 1, (ks + 1) & 1);
    __syncthreads();
  }
  MMA((NKS - 1) & 1);
  const int col0 = n0 + wc * 32 + (lane & 15);
  const int rsub = (lane >> 4) * 4;
#pragma unroll
  for (int mi = 0; mi < 4; ++mi)
#pragma unroll
    for (int ni = 0; ni < 2; ++ni)
#pragma unroll
      for (int r = 0; r < 4; ++r)
        C[(size_t)(m0 + wr * 64 + mi * 16 + rsub + r) * N_ + (col0 + ni * 16)] =
            acc[mi][ni][r];
}

extern "C" void kernel_launch(void* const* d_in, const int* in_sizes, int n_in,
                              void* d_out, int out_size, void* d_ws, size_t ws_size,
                              hipStream_t stream) {
  const float* x = (const float*)d_in[0];
  const float* w = (const float*)d_in[1];
  float* out = (float*)d_out;
  const int M = in_sizes[0] / K_;            // 32768
  if (ws_size >= (size_t)(512 * 1024)) {
    ushort* Wp = (ushort*)d_ws;
    pack_w<<<dim3(128), dim3(256), 0, stream>>>(w, Wp);
    dim3 grid((M / 128) * (N_ / 64));        // 2048 blocks
    gemm_reg<<<grid, dim3(256), 0, stream>>>(x, Wp, out);
  } else {
    dim3 grid((M / 128) * (N_ / 128));       // 1024 blocks
    gemm_fb<<<grid, dim3(512), 0, stream>>>(x, w, out);
  }
}

// Round 6
// 50.163 us; speedup vs baseline: 1.7217x; 1.7217x over previous
//
#include <hip/hip_runtime.h>
#include <hip/hip_bf16.h>

using f32x4   = __attribute__((ext_vector_type(4))) float;
using bf16x8  = __attribute__((ext_vector_type(8))) short;
using ushort8 = __attribute__((ext_vector_type(8))) unsigned short;

constexpr int N_ = 512;
constexpr int K_ = 512;
constexpr int BM = 256, BN = 64, BK = 64;   // block tile; 8 waves x 32 rows
constexpr int BMW = 32;                     // rows per wave
constexpr int LDSK = 72;                    // 64 + 8 pad
constexpr int NKS = K_ / BK;                // 8

__device__ inline ushort f2bf(float f) {
  union { __hip_bfloat16 h; ushort u; } c;
  c.h = __float2bfloat16(f);
  return c.u;
}

// ---- pre-kernel: pack W[512][512] fp32 -> fragment-linear bf16 ----
// frag f = n_tile*16 + kc ; lane l holds W[n_tile*16 + (l&15)][kc*32 + (l>>4)*8 ..+8]
// 64 lanes x 16 B contiguous = 1 KB per frag.
__global__ __launch_bounds__(256)
void pack_w(const float* __restrict__ W, ushort* __restrict__ P) {
  const int tau = blockIdx.x * 256 + threadIdx.x;   // 0..32767
  const int l = tau & 63, f = tau >> 6;
  const int row = (f >> 4) * 16 + (l & 15);
  const int kb  = (f & 15) * 32 + (l >> 4) * 8;
  const float* s = W + (size_t)row * K_ + kb;
  f32x4 v0 = *reinterpret_cast<const f32x4*>(s);
  f32x4 v1 = *reinterpret_cast<const f32x4*>(s + 4);
  ushort8 o;
  o[0] = f2bf(v0.x); o[1] = f2bf(v0.y); o[2] = f2bf(v0.z); o[3] = f2bf(v0.w);
  o[4] = f2bf(v1.x); o[5] = f2bf(v1.y); o[6] = f2bf(v1.z); o[7] = f2bf(v1.w);
  *reinterpret_cast<ushort8*>(P + (size_t)tau * 8) = o;
}

// ---- main GEMM: wave-autonomous pipelines, ZERO __syncthreads ----
// Each wave: private dbuf LDS slice for its 32xBK A sub-tile (coalesced
// f32x4 staging + in-reg cvt), B frags from packed global (L1-hot, shared
// across the block's 8 waves). Wave tile 32x64.
__global__ __launch_bounds__(512, 4)
void gemm_wa(const float* __restrict__ X, const ushort* __restrict__ Wp,
             float* __restrict__ C) {
  __shared__ ushort As[8][2][BMW * LDSK];

  const int t    = threadIdx.x;
  const int lane = t & 63;
  const int wv   = t >> 6;      // 0..7

  // XCD-aware bijective swizzle: 1024 blocks = 8 XCDs x 128; bn fastest so a
  // row-panel's 8 bn-blocks are consecutive -> share the XCD's L2 for X.
  const int cpx = gridDim.x >> 3;
  const int bid = (blockIdx.x & 7) * cpx + (blockIdx.x >> 3);
  const int bn  = bid & 7;      // 512/64 = 8 col tiles
  const int bm  = bid >> 3;
  const int m0 = bm * BM + wv * BMW;   // this wave's first row
  const int n0 = bn * BN;

  // A staging (per wave, coalesced): load i covers rows i*4+(lane>>4),
  // cols (lane&15)*4 .. +4  -> 4 x 256B contiguous segments per instruction.
  const int srow = lane >> 4;          // 0..3
  const int scol = (lane & 15) * 4;    // 0..60
  const float* ap = X + (size_t)(m0 + srow) * K_ + scol;

  // B frag base: n_tile = bn*4 + ni, elem off = (n_tile*16 + kc)*512 + lane*8
  const ushort* bp = Wp + (size_t)(bn * 4) * 16 * 512 + lane * 8;

  ushort* lds0 = &As[wv][0][0];
  ushort* lds1 = &As[wv][1][0];

  f32x4 acc[2][4] = {};
  f32x4 ra[8];

  auto LOAD = [&](int ks) {
#pragma unroll
    for (int i = 0; i < 8; ++i)
      ra[i] = *reinterpret_cast<const f32x4*>(ap + (size_t)(i * 4) * K_ + ks * BK);
  };

  auto STAGE = [&](ushort* buf) {      // waits vmcnt for ra, cvt, ds_write
#pragma unroll
    for (int i = 0; i < 8; ++i) {
      ushort4 h;
      h.x = f2bf(ra[i].x); h.y = f2bf(ra[i].y);
      h.z = f2bf(ra[i].z); h.w = f2bf(ra[i].w);
      *reinterpret_cast<ushort4*>(&buf[(i * 4 + srow) * LDSK + scol]) = h;
    }
  };

  auto MMA = [&](const ushort* buf, int ks) {
    bf16x8 b[8];
#pragma unroll
    for (int kk = 0; kk < 2; ++kk)
#pragma unroll
      for (int ni = 0; ni < 4; ++ni)
        b[kk * 4 + ni] = *reinterpret_cast<const bf16x8*>(
            bp + (size_t)(ni * 16 + ks * 2 + kk) * 512);
    bf16x8 a4[2][2];
#pragma unroll
    for (int kk = 0; kk < 2; ++kk)
#pragma unroll
      for (int mi = 0; mi < 2; ++mi)
        a4[kk][mi] = *reinterpret_cast<const bf16x8*>(
            &buf[(mi * 16 + (lane & 15)) * LDSK + kk * 32 + (lane >> 4) * 8]);
#pragma unroll
    for (int kk = 0; kk < 2; ++kk)
#pragma unroll
      for (int mi = 0; mi < 2; ++mi)
#pragma unroll
        for (int ni = 0; ni < 4; ++ni)
          acc[mi][ni] = __builtin_amdgcn_mfma_f32_16x16x32_bf16(
              a4[kk][mi], b[kk * 4 + ni], acc[mi][ni], 0, 0, 0);
  };

  LOAD(0);
  STAGE(lds0);

#pragma unroll
  for (int ks = 0; ks < NKS; ++ks) {
    if (ks + 1 < NKS) LOAD(ks + 1);            // issue next A loads early
    MMA((ks & 1) ? lds1 : lds0, ks);           // consume current buffer
    if (ks + 1 < NKS) STAGE((ks & 1) ? lds0 : lds1);
  }

  // store: C/D layout col = lane&15, row = (lane>>4)*4 + reg
  const int col0 = n0 + (lane & 15);
  const int rsub = (lane >> 4) * 4;
#pragma unroll
  for (int mi = 0; mi < 2; ++mi)
#pragma unroll
    for (int ni = 0; ni < 4; ++ni)
#pragma unroll
      for (int r = 0; r < 4; ++r)
        C[(size_t)(m0 + mi * 16 + rsub + r) * N_ + (col0 + ni * 16)] =
            acc[mi][ni][r];
}

// ---- fallback (round-3 kernel) if ws is too small for the W pack ----
constexpr int FBM = 128, FBN = 128;

__global__ __launch_bounds__(512, 4)
void gemm_fb(const float* __restrict__ X, const float* __restrict__ W,
             float* __restrict__ C) {
  __shared__ ushort Asf[2][FBM * LDSK];
  __shared__ ushort Bsf[2][FBN * LDSK];
  const int t = threadIdx.x, lane = t & 63, wave = t >> 6;
  const int wr = wave >> 2, wc = wave & 3;
  const int cpx = gridDim.x >> 3;
  const int bid = (blockIdx.x & 7) * cpx + (blockIdx.x >> 3);
  const int bn = bid & 3, bm = bid >> 2;
  const int m0 = bm * FBM, n0 = bn * FBN;
  const int sr = t >> 4, sc = (t & 15) * 4;
  const float* xp = X + (size_t)(m0 + sr) * K_ + sc;
  const float* wp = W + (size_t)(n0 + sr) * K_ + sc;
  f32x4 acc[4][2] = {};
  f32x4 ra[2][4], rb[2][4];
  auto LOAD = [&](int set, int ks) {
#pragma unroll
    for (int i = 0; i < 4; ++i) {
      ra[set][i] = *reinterpret_cast<const f32x4*>(xp + (size_t)(i * 32) * K_ + ks * 64);
      rb[set][i] = *reinterpret_cast<const f32x4*>(wp + (size_t)(i * 32) * K_ + ks * 64);
    }
  };
  auto STAGE = [&](int set, int buf) {
#pragma unroll
    for (int i = 0; i < 4; ++i) {
      ushort4 ha, hb;
      ha.x = f2bf(ra[set][i].x); ha.y = f2bf(ra[set][i].y);
      ha.z = f2bf(ra[set][i].z); ha.w = f2bf(ra[set][i].w);
      hb.x = f2bf(rb[set][i].x); hb.y = f2bf(rb[set][i].y);
      hb.z = f2bf(rb[set][i].z); hb.w = f2bf(rb[set][i].w);
      *reinterpret_cast<ushort4*>(&Asf[buf][(sr + 32 * i) * LDSK + sc]) = ha;
      *reinterpret_cast<ushort4*>(&Bsf[buf][(sr + 32 * i) * LDSK + sc]) = hb;
    }
  };
  auto MMA = [&](int buf) {
#pragma unroll
    for (int kk = 0; kk < 2; ++kk) {
      const int kof = kk * 32 + (lane >> 4) * 8;
      bf16x8 aa[4], bb[2];
#pragma unroll
      for (int mi = 0; mi < 4; ++mi)
        aa[mi] = *reinterpret_cast<const bf16x8*>(
            &Asf[buf][(wr * 64 + mi * 16 + (lane & 15)) * LDSK + kof]);
#pragma unroll
      for (int ni = 0; ni < 2; ++ni)
        bb[ni] = *reinterpret_cast<const bf16x8*>(
            &Bsf[buf][(wc * 32 + ni * 16 + (lane & 15)) * LDSK + kof]);
#pragma unroll
      for (int mi = 0; mi < 4; ++mi)
#pragma unroll
        for (int ni = 0; ni < 2; ++ni)
          acc[mi][ni] = __builtin_amdgcn_mfma_f32_16x16x32_bf16(aa[mi], bb[ni],
                                                                acc[mi][ni], 0, 0, 0);
    }
  };
  LOAD(0, 0); LOAD(1, 1); STAGE(0, 0);
  __syncthreads();
#pragma unroll
  for (int ks = 0; ks < NKS - 1; ++ks) {
    if (ks + 2 < NKS) LOAD(ks & 1, ks + 2);
    MMA(ks & 1);
    STAGE((ks + 1) & 1, (ks + 1) & 1);
    __syncthreads();
  }
  MMA((NKS - 1) & 1);
  const int col0 = n0 + wc * 32 + (lane & 15);
  const int rsub = (lane >> 4) * 4;
#pragma unroll
  for (int mi = 0; mi < 4; ++mi)
#pragma unroll
    for (int ni = 0; ni < 2; ++ni)
#pragma unroll
      for (int r = 0; r < 4; ++r)
        C[(size_t)(m0 + wr * 64 + mi * 16 + rsub + r) * N_ + (col0 + ni * 16)] =
            acc[mi][ni][r];
}

extern "C" void kernel_launch(void* const* d_in, const int* in_sizes, int n_in,
                              void* d_out, int out_size, void* d_ws, size_t ws_size,
                              hipStream_t stream) {
  const float* x = (const float*)d_in[0];
  const float* w = (const float*)d_in[1];
  float* out = (float*)d_out;
  const int M = in_sizes[0] / K_;            // 32768
  if (ws_size >= (size_t)(512 * 1024)) {
    ushort* Wp = (ushort*)d_ws;
    pack_w<<<dim3(128), dim3(256), 0, stream>>>(w, Wp);
    dim3 grid((M / BM) * (N_ / BN));         // 128 * 8 = 1024 blocks
    gemm_wa<<<grid, dim3(512), 0, stream>>>(x, Wp, out);
  } else {
    dim3 grid((M / FBM) * (N_ / FBN));       // 1024 blocks
    gemm_fb<<<grid, dim3(512), 0, stream>>>(x, w, out);
  }
}